// Round 3
// baseline (4638.763 us; speedup 1.0000x reference)
//
#include <hip/hip_runtime.h>
#include <hip/hip_cooperative_groups.h>

namespace cg = cooperative_groups;

#define PROP_ALPHA 0.1f
#define PROP_KSTEPS 10

typedef _Float16 half_t;
typedef __attribute__((ext_vector_type(4))) _Float16 half4v;
typedef __attribute__((ext_vector_type(8))) _Float16 half8v;

__device__ inline unsigned int f2h15(float w) {
    half_t h = (half_t)w;
    return (unsigned int)__builtin_bit_cast(unsigned short, h) & 0x7FFFu;
}
__device__ inline float h15_2f(unsigned int bits) {
    half_t h = __builtin_bit_cast(half_t, (unsigned short)(bits & 0x7FFFu));
    return (float)h;
}

// 8-channel load/store helpers (16 B for fp16, 2x16 B for fp32)
__device__ inline void ld8f(const half_t* __restrict__ p, float* z) {
    half8v v = *reinterpret_cast<const half8v*>(p);
    #pragma unroll
    for (int j = 0; j < 8; ++j) z[j] = (float)v[j];
}
__device__ inline void ld8f(const float* __restrict__ p, float* z) {
    float4 a = *reinterpret_cast<const float4*>(p);
    float4 b = *reinterpret_cast<const float4*>(p + 4);
    z[0] = a.x; z[1] = a.y; z[2] = a.z; z[3] = a.w;
    z[4] = b.x; z[5] = b.y; z[6] = b.z; z[7] = b.w;
}
__device__ inline void st8(half_t* __restrict__ p, const float* r) {
    half8v v;
    #pragma unroll
    for (int j = 0; j < 8; ++j) v[j] = (half_t)r[j];
    *reinterpret_cast<half8v*>(p) = v;
}
__device__ inline void st8(float* __restrict__ p, const float* r) {
    float4 a = {r[0], r[1], r[2], r[3]};
    float4 b = {r[4], r[5], r[6], r[7]};
    *reinterpret_cast<float4*>(p) = a;
    *reinterpret_cast<float4*>(p + 4) = b;
}

// ---------------- CSR build ----------------

__global__ void hist_kernel(const int* __restrict__ dst, int* __restrict__ degI, int E) {
    int e = blockIdx.x * blockDim.x + threadIdx.x;
    if (e < E) atomicAdd(&degI[dst[e]], 1);
}

__global__ void dinv_kernel(const int* __restrict__ degI, float* __restrict__ dinv, int N) {
    int i = blockIdx.x * blockDim.x + threadIdx.x;
    if (i < N) {
        float d = (float)(degI[i] + 1);   // + self loop
        dinv[i] = rsqrtf(d);
    }
}

// rows padded to multiple of 8 slots (pad entries stay 0 => norm 0, src 0)
__global__ __launch_bounds__(256) void scan1_kernel(const int* __restrict__ degI,
                                                    int* __restrict__ rowptr,
                                                    int* __restrict__ blockSums, int N) {
    __shared__ int s[256];
    int t = threadIdx.x;
    int idx = blockIdx.x * 256 + t;
    s[t] = (idx < N) ? ((degI[idx] + 7) & ~7) : 0;
    __syncthreads();
    for (int off = 1; off < 256; off <<= 1) {
        int x = (t >= off) ? s[t - off] : 0;
        __syncthreads();
        s[t] += x;
        __syncthreads();
    }
    if (idx < N) rowptr[idx + 1] = s[t];
    if (t == 255) blockSums[blockIdx.x] = s[255];
    if (blockIdx.x == 0 && t == 0) rowptr[0] = 0;
}

__global__ __launch_bounds__(256) void scan2_kernel(int* __restrict__ blockSums, int nB) {
    __shared__ int s[256];
    int t = threadIdx.x;
    s[t] = (t < nB) ? blockSums[t] : 0;
    __syncthreads();
    for (int off = 1; off < 256; off <<= 1) {
        int x = (t >= off) ? s[t - off] : 0;
        __syncthreads();
        s[t] += x;
        __syncthreads();
    }
    if (t < nB) blockSums[t] = (t == 0) ? 0 : s[t - 1];
}

__global__ void scan3_kernel(int* __restrict__ rowptr, const int* __restrict__ blockSums,
                             int N) {
    int idx = blockIdx.x * 256 + threadIdx.x;
    if (idx < N) rowptr[idx + 1] += blockSums[blockIdx.x];
}

// edata[p] = src<<15 | fp16bits(norm) sans sign — plain store (L2-resident)
__global__ void scatter_kernel(const int* __restrict__ src, const int* __restrict__ dst,
                               const int* __restrict__ rowptr, int* __restrict__ rowctr,
                               const float* __restrict__ dinv,
                               int* __restrict__ edata, int E) {
    int e = blockIdx.x * blockDim.x + threadIdx.x;
    if (e < E) {
        int d = dst[e], s = src[e];
        int p = rowptr[d] + atomicAdd(&rowctr[d], 1);
        edata[p] = (int)(((unsigned int)s << 15) | f2h15(dinv[s] * dinv[d]));
    }
}

// ---------------- fused MLP: h2 = relu(zx@W3 + v*b3^T)@W4 + b4 ----------------

__global__ __launch_bounds__(256) void fusedmlp_kernel(const half_t* __restrict__ zx,
                                                       const float* __restrict__ v,
                                                       const float* __restrict__ W3,
                                                       const float* __restrict__ b3,
                                                       const float* __restrict__ W4,
                                                       const float* __restrict__ b4,
                                                       float* __restrict__ h2, int N) {
    __shared__ float Ws[64 * 128];     // 32 KB: W3 [k][128] then W4 [k][64]
    __shared__ half_t zsT[64 * 36];    // [k][row] fp16, padded stride 36
    __shared__ half_t ts[32 * 132];    // [row][k] fp16, padded stride 132
    __shared__ float vs[32];
    int t = threadIdx.x;
    int r0 = blockIdx.x * 32;
    int rows = min(32, N - r0);

    for (int idx = t; idx < 64 * 128; idx += 256) Ws[idx] = W3[idx];
    for (int idx = t; idx < 32 * 64; idx += 256) {
        int r = idx >> 6, c = idx & 63;
        zsT[c * 36 + r] = (r < rows) ? zx[(size_t)(r0 + r) * 64 + c] : (half_t)0.0f;
    }
    if (t < 32) vs[t] = (t < rows) ? v[r0 + t] : 0.0f;
    __syncthreads();

    // ---- layer 1: ts = relu(z @ W3 + v*b3^T) ----
    {
        int cq = t & 31, rq = t >> 5;
        int cb = cq * 4, rb = rq * 4;
        float4 b3v = *reinterpret_cast<const float4*>(&b3[cb]);
        float a[4][4];
        #pragma unroll
        for (int ri = 0; ri < 4; ++ri) {
            float vv = vs[rb + ri];
            a[ri][0] = vv * b3v.x; a[ri][1] = vv * b3v.y;
            a[ri][2] = vv * b3v.z; a[ri][3] = vv * b3v.w;
        }
        #pragma unroll 4
        for (int k = 0; k < 64; ++k) {
            half4v zh = *reinterpret_cast<const half4v*>(&zsT[k * 36 + rb]);
            float z0 = (float)zh.x, z1 = (float)zh.y, z2 = (float)zh.z, z3 = (float)zh.w;
            float4 wq = *reinterpret_cast<const float4*>(&Ws[k * 128 + cb]);
            a[0][0] += z0 * wq.x; a[0][1] += z0 * wq.y;
            a[0][2] += z0 * wq.z; a[0][3] += z0 * wq.w;
            a[1][0] += z1 * wq.x; a[1][1] += z1 * wq.y;
            a[1][2] += z1 * wq.z; a[1][3] += z1 * wq.w;
            a[2][0] += z2 * wq.x; a[2][1] += z2 * wq.y;
            a[2][2] += z2 * wq.z; a[2][3] += z2 * wq.w;
            a[3][0] += z3 * wq.x; a[3][1] += z3 * wq.y;
            a[3][2] += z3 * wq.z; a[3][3] += z3 * wq.w;
        }
        #pragma unroll
        for (int ri = 0; ri < 4; ++ri) {
            half4v o;
            o.x = (half_t)fmaxf(a[ri][0], 0.0f); o.y = (half_t)fmaxf(a[ri][1], 0.0f);
            o.z = (half_t)fmaxf(a[ri][2], 0.0f); o.w = (half_t)fmaxf(a[ri][3], 0.0f);
            *reinterpret_cast<half4v*>(&ts[(rb + ri) * 132 + cb]) = o;
        }
    }
    __syncthreads();
    for (int idx = t; idx < 128 * 64; idx += 256) Ws[idx] = W4[idx];
    __syncthreads();

    // ---- layer 2: h2 = t @ W4 + b4 (row-major ts reads) ----
    {
        int cg2 = t & 15, rg = t >> 4;
        int cb = cg2 * 4, rb = rg * 2;
        float4 b4v = *reinterpret_cast<const float4*>(&b4[cb]);
        float a[2][4];
        #pragma unroll
        for (int ri = 0; ri < 2; ++ri) {
            a[ri][0] = b4v.x; a[ri][1] = b4v.y; a[ri][2] = b4v.z; a[ri][3] = b4v.w;
        }
        #pragma unroll 4
        for (int k = 0; k < 128; ++k) {
            float t0 = (float)ts[rb * 132 + k];
            float t1 = (float)ts[(rb + 1) * 132 + k];
            float4 wq = *reinterpret_cast<const float4*>(&Ws[k * 64 + cb]);
            a[0][0] += t0 * wq.x; a[0][1] += t0 * wq.y;
            a[0][2] += t0 * wq.z; a[0][3] += t0 * wq.w;
            a[1][0] += t1 * wq.x; a[1][1] += t1 * wq.y;
            a[1][2] += t1 * wq.z; a[1][3] += t1 * wq.w;
        }
        #pragma unroll
        for (int ri = 0; ri < 2; ++ri) {
            int r = rb + ri;
            if (r < rows) {
                float4 o = {a[ri][0], a[ri][1], a[ri][2], a[ri][3]};
                *reinterpret_cast<float4*>(&h2[(size_t)(r0 + r) * 64 + cb]) = o;
            }
        }
    }
}

// ---------------- fused propagation: 10 steps in ONE cooperative launch -------
// One node per wave per grid-stride iteration. Lane -> (edge slot g = lane>>3,
// channel base c = (lane&7)*8). One gather = 8 edges x 128 B row (1 KB/instr).
// Rows padded to x8 -> no tails. grid.sync() between steps; __threadfence for
// cross-XCD visibility of z. No early returns: all threads reach every sync.

template <bool PHASE1>
__global__ __launch_bounds__(256, 4) void propfused_kernel(
        const float* __restrict__ xf,     // gather src for s=0 AND the alpha-h term
        const int* __restrict__ rowptr,
        const int* __restrict__ edata,
        const float* __restrict__ dinv,
        half_t* __restrict__ zA,
        half_t* __restrict__ zB,
        float* __restrict__ outF,         // phase2: final fp32 out; phase1: unused
        float* __restrict__ vA,
        float* __restrict__ vB,
        int N) {
    cg::grid_group grid = cg::this_grid();
    const int wave = threadIdx.x >> 6;
    const int lane = threadIdx.x & 63;
    const int g = lane >> 3;              // edge slot 0..7
    const int c = (lane & 7) << 3;        // channel base (8 channels/lane)
    const int W = gridDim.x * 4;          // total waves
    const int w0 = blockIdx.x * 4 + wave;

    for (int s = 0; s < PROP_KSTEPS; ++s) {
        const half_t* zin16 = (s & 1) ? zA : zB;       // valid for s>=1
        half_t*       zout16 = (s & 1) ? zB : zA;
        const float*  vin = (s & 1) ? vA : vB;         // phase1, s>=1
        float*        vout = (s & 1) ? vB : vA;
        const bool lastOut = (!PHASE1) && (s == PROP_KSTEPS - 1);

        for (int node = w0; node < N; node += W) {
            int nd = __builtin_amdgcn_readfirstlane(node);
            int beg = rowptr[nd];
            int end = rowptr[nd + 1];      // end-beg multiple of 8
            float a[8] = {0.f, 0.f, 0.f, 0.f, 0.f, 0.f, 0.f, 0.f};
            float vacc = 0.f;

            if (s == 0) {
                for (int e = beg; e < end; e += 8) {
                    unsigned int p = (unsigned int)edata[e + g];
                    int sn = p >> 15;
                    float n = h15_2f(p);                 // pads: n == 0
                    float z[8];
                    ld8f(&xf[(size_t)sn * 64 + c], z);
                    if (PHASE1) vacc += n;               // v_in == ones
                    #pragma unroll
                    for (int j = 0; j < 8; ++j) a[j] += n * z[j];
                }
            } else {
                for (int e = beg; e < end; e += 8) {
                    unsigned int p = (unsigned int)edata[e + g];
                    int sn = p >> 15;
                    float n = h15_2f(p);
                    float z[8];
                    ld8f(&zin16[(size_t)sn * 64 + c], z);
                    if (PHASE1) vacc += n * vin[sn];     // pads: n==0 masks
                    #pragma unroll
                    for (int j = 0; j < 8; ++j) a[j] += n * z[j];
                }
            }

            // reduce across 8 edge slots; (lane&7) channel slice preserved
            #pragma unroll
            for (int m = 8; m <= 32; m <<= 1) {
                #pragma unroll
                for (int j = 0; j < 8; ++j) a[j] += __shfl_xor(a[j], m);
                if (PHASE1) vacc += __shfl_xor(vacc, m);
            }

            if (lane < 8) {
                int cw = lane << 3;
                size_t base = (size_t)nd * 64 + cw;
                float di = dinv[nd];
                float dd = di * di;
                float self[8];
                if (s == 0) ld8f(&xf[base], self);
                else        ld8f(&zin16[base], self);
                float hh[8];
                ld8f(&xf[base], hh);
                float r[8];
                #pragma unroll
                for (int j = 0; j < 8; ++j)
                    r[j] = (1.0f - PROP_ALPHA) * (a[j] + dd * self[j])
                         + PROP_ALPHA * hh[j];
                if (lastOut) st8(&outF[base], r);
                else         st8(&zout16[base], r);
                if (PHASE1 && lane == 0) {
                    float selfv = (s == 0) ? 1.0f : vin[nd];
                    vout[nd] = (1.0f - PROP_ALPHA) * (vacc + dd * selfv) + PROP_ALPHA;
                }
            }
        }
        if (s != PROP_KSTEPS - 1) {
            __threadfence();               // cross-XCD visibility of z/v writes
            grid.sync();
        }
    }
}

// ---------------- launch ----------------

extern "C" void kernel_launch(void* const* d_in, const int* in_sizes, int n_in,
                              void* d_out, int out_size, void* d_ws, size_t ws_size,
                              hipStream_t stream) {
    const float* x  = (const float*)d_in[0];
    const int*   ei = (const int*)d_in[1];
    const float* W3 = (const float*)d_in[2];
    const float* b3 = (const float*)d_in[3];
    const float* W4 = (const float*)d_in[4];
    const float* b4 = (const float*)d_in[5];
    float* out = (float*)d_out;

    int N = in_sizes[0] / 64;   // IN_CH = 64
    int E = in_sizes[1] / 2;
    const int* srcA = ei;
    const int* dstA = ei + E;

    char* ws = (char*)d_ws;
    size_t off = 0;
    auto alloc = [&](size_t bytes) -> void* {
        void* p = ws + off;
        off = (off + bytes + 255) & ~(size_t)255;
        return p;
    };

    int nScanB = (N + 255) / 256;
    size_t ePadMax = (size_t)E + 8 * (size_t)N;   // upper bound on padded slots

    int*    degI   = (int*)alloc((size_t)N * 4);
    int*    rowptr = (int*)alloc(((size_t)N + 1) * 4);
    int*    rowctr = (int*)alloc((size_t)N * 4);
    int*    bsums  = (int*)alloc((size_t)nScanB * 4);
    float*  dinv   = (float*)alloc((size_t)N * 4);
    int*    edata  = (int*)alloc(ePadMax * 4);
    float*  vA     = (float*)alloc((size_t)N * 4);
    float*  vB     = (float*)alloc((size_t)N * 4);
    half_t* z16A   = (half_t*)alloc((size_t)N * 64 * 2);
    half_t* z16B   = (half_t*)alloc((size_t)N * 64 * 2);
    float*  hbuf   = (float*)alloc((size_t)N * 64 * 4);

    hipMemsetAsync(degI, 0, (size_t)N * 4, stream);
    hipMemsetAsync(rowctr, 0, (size_t)N * 4, stream);
    hipMemsetAsync(edata, 0, ePadMax * 4, stream);   // pad slots read as norm=0

    // --- CSR build (padded rows) ---
    hist_kernel<<<(E + 255) / 256, 256, 0, stream>>>(dstA, degI, E);
    dinv_kernel<<<(N + 255) / 256, 256, 0, stream>>>(degI, dinv, N);
    scan1_kernel<<<nScanB, 256, 0, stream>>>(degI, rowptr, bsums, N);
    scan2_kernel<<<1, 256, 0, stream>>>(bsums, nScanB);
    scan3_kernel<<<nScanB, 256, 0, stream>>>(rowptr, bsums, N);
    scatter_kernel<<<(E + 255) / 256, 256, 0, stream>>>(srcA, dstA, rowptr, rowctr,
                                                        dinv, edata, E);

    // --- cooperative grid sizing: all blocks must be co-resident ---
    int maxB1 = 0, maxB2 = 0;
    hipOccupancyMaxActiveBlocksPerMultiprocessor(&maxB1, propfused_kernel<true>, 256, 0);
    hipOccupancyMaxActiveBlocksPerMultiprocessor(&maxB2, propfused_kernel<false>, 256, 0);
    int bpc = maxB1 < maxB2 ? maxB1 : maxB2;
    if (bpc < 1) bpc = 1;
    if (bpc > 8) bpc = 8;
    int wantBlocks = (N + 3) / 4;
    int grid = bpc * 256;                 // 256 CUs on MI355X
    if (grid > wantBlocks) grid = wantBlocks;

    float* nullF = nullptr;

    // --- prop1 (fused 10 steps): zx = M^10*x (fp16 in z16B), v = M^10*ones (vB)
    {
        void* args[] = {(void*)&x, (void*)&rowptr, (void*)&edata, (void*)&dinv,
                        (void*)&z16A, (void*)&z16B, (void*)&nullF,
                        (void*)&vA, (void*)&vB, (void*)&N};
        hipLaunchCooperativeKernel(propfused_kernel<true>, dim3(grid), dim3(256),
                                   args, 0u, stream);
    }

    // --- h2 = relu(zx@W3 + v*b3^T)@W4 + b4 ---
    fusedmlp_kernel<<<(N + 31) / 32, 256, 0, stream>>>(z16B, vB, W3, b3, W4, b4, hbuf, N);

    // --- prop2 (fused 10 steps): out = M^10*h2 ---
    {
        void* args[] = {(void*)&hbuf, (void*)&rowptr, (void*)&edata, (void*)&dinv,
                        (void*)&z16A, (void*)&z16B, (void*)&out,
                        (void*)&vA, (void*)&vB, (void*)&N};
        hipLaunchCooperativeKernel(propfused_kernel<false>, dim3(grid), dim3(256),
                                   args, 0u, stream);
    }
}

// Round 4
// 997.401 us; speedup vs baseline: 4.6509x; 4.6509x over previous
//
#include <hip/hip_runtime.h>

#define PROP_ALPHA 0.1f
#define PROP_KSTEPS 10

typedef _Float16 half_t;
typedef __attribute__((ext_vector_type(4))) _Float16 half4v;

__device__ inline unsigned int f2h15(float w) {
    half_t h = (half_t)w;
    return (unsigned int)__builtin_bit_cast(unsigned short, h) & 0x7FFFu;
}
__device__ inline float h15_2f(unsigned int bits) {
    half_t h = __builtin_bit_cast(half_t, (unsigned short)(bits & 0x7FFFu));
    return (float)h;
}
__device__ inline float4 h4tof4(const half_t* __restrict__ p) {
    half4v v = *reinterpret_cast<const half4v*>(p);
    float4 r; r.x = (float)v.x; r.y = (float)v.y; r.z = (float)v.z; r.w = (float)v.w;
    return r;
}

// ---------------- CSR build ----------------

__global__ void hist_kernel(const int* __restrict__ dst, int* __restrict__ degI, int E) {
    int e = blockIdx.x * blockDim.x + threadIdx.x;
    if (e < E) atomicAdd(&degI[dst[e]], 1);
}

__global__ void dinv_kernel(const int* __restrict__ degI, float* __restrict__ dinv, int N) {
    int i = blockIdx.x * blockDim.x + threadIdx.x;
    if (i < N) {
        float d = (float)(degI[i] + 1);   // + self loop
        dinv[i] = rsqrtf(d);
    }
}

// rows padded to multiple of 8 slots (pad entries stay 0 => norm 0, src 0)
__global__ __launch_bounds__(256) void scan1_kernel(const int* __restrict__ degI,
                                                    int* __restrict__ rowptr,
                                                    int* __restrict__ blockSums, int N) {
    __shared__ int s[256];
    int t = threadIdx.x;
    int idx = blockIdx.x * 256 + t;
    s[t] = (idx < N) ? ((degI[idx] + 7) & ~7) : 0;
    __syncthreads();
    for (int off = 1; off < 256; off <<= 1) {
        int x = (t >= off) ? s[t - off] : 0;
        __syncthreads();
        s[t] += x;
        __syncthreads();
    }
    if (idx < N) rowptr[idx + 1] = s[t];
    if (t == 255) blockSums[blockIdx.x] = s[255];
    if (blockIdx.x == 0 && t == 0) rowptr[0] = 0;
}

__global__ __launch_bounds__(256) void scan2_kernel(int* __restrict__ blockSums, int nB) {
    __shared__ int s[256];
    int t = threadIdx.x;
    s[t] = (t < nB) ? blockSums[t] : 0;
    __syncthreads();
    for (int off = 1; off < 256; off <<= 1) {
        int x = (t >= off) ? s[t - off] : 0;
        __syncthreads();
        s[t] += x;
        __syncthreads();
    }
    if (t < nB) blockSums[t] = (t == 0) ? 0 : s[t - 1];
}

__global__ void scan3_kernel(int* __restrict__ rowptr, const int* __restrict__ blockSums,
                             int N) {
    int idx = blockIdx.x * 256 + threadIdx.x;
    if (idx < N) rowptr[idx + 1] += blockSums[blockIdx.x];
}

// edata[p] = src<<15 | fp16bits(norm) sans sign — plain store (L2-resident)
__global__ void scatter_kernel(const int* __restrict__ src, const int* __restrict__ dst,
                               const int* __restrict__ rowptr, int* __restrict__ rowctr,
                               const float* __restrict__ dinv,
                               int* __restrict__ edata, int E) {
    int e = blockIdx.x * blockDim.x + threadIdx.x;
    if (e < E) {
        int d = dst[e], s = src[e];
        int p = rowptr[d] + atomicAdd(&rowctr[d], 1);
        edata[p] = (int)(((unsigned int)s << 15) | f2h15(dinv[s] * dinv[d]));
    }
}

// ---------------- fused MLP: h2 = relu(zx@W3 + v*b3^T)@W4 + b4 ----------------
// zx comes in as two fp16 channel-planes (ch 0-31, ch 32-63).

__global__ __launch_bounds__(256) void fusedmlp_kernel(const half_t* __restrict__ zLo,
                                                       const half_t* __restrict__ zHi,
                                                       const float* __restrict__ v,
                                                       const float* __restrict__ W3,
                                                       const float* __restrict__ b3,
                                                       const float* __restrict__ W4,
                                                       const float* __restrict__ b4,
                                                       float* __restrict__ h2, int N) {
    __shared__ float Ws[64 * 128];     // 32 KB: W3 [k][128] then W4 [k][64]
    __shared__ half_t zsT[64 * 36];    // [k][row] fp16, padded stride 36
    __shared__ half_t ts[32 * 132];    // [row][k] fp16, padded stride 132
    __shared__ float vs[32];
    int t = threadIdx.x;
    int r0 = blockIdx.x * 32;
    int rows = min(32, N - r0);

    for (int idx = t; idx < 64 * 128; idx += 256) Ws[idx] = W3[idx];
    for (int idx = t; idx < 32 * 64; idx += 256) {
        int r = idx >> 6, c = idx & 63;
        half_t val = (half_t)0.0f;
        if (r < rows)
            val = (c < 32) ? zLo[(size_t)(r0 + r) * 32 + c]
                           : zHi[(size_t)(r0 + r) * 32 + (c - 32)];
        zsT[c * 36 + r] = val;
    }
    if (t < 32) vs[t] = (t < rows) ? v[r0 + t] : 0.0f;
    __syncthreads();

    // ---- layer 1: ts = relu(z @ W3 + v*b3^T) ----
    {
        int cq = t & 31, rq = t >> 5;
        int cb = cq * 4, rb = rq * 4;
        float4 b3v = *reinterpret_cast<const float4*>(&b3[cb]);
        float a[4][4];
        #pragma unroll
        for (int ri = 0; ri < 4; ++ri) {
            float vv = vs[rb + ri];
            a[ri][0] = vv * b3v.x; a[ri][1] = vv * b3v.y;
            a[ri][2] = vv * b3v.z; a[ri][3] = vv * b3v.w;
        }
        #pragma unroll 4
        for (int k = 0; k < 64; ++k) {
            half4v zh = *reinterpret_cast<const half4v*>(&zsT[k * 36 + rb]);
            float z0 = (float)zh.x, z1 = (float)zh.y, z2 = (float)zh.z, z3 = (float)zh.w;
            float4 wq = *reinterpret_cast<const float4*>(&Ws[k * 128 + cb]);
            a[0][0] += z0 * wq.x; a[0][1] += z0 * wq.y;
            a[0][2] += z0 * wq.z; a[0][3] += z0 * wq.w;
            a[1][0] += z1 * wq.x; a[1][1] += z1 * wq.y;
            a[1][2] += z1 * wq.z; a[1][3] += z1 * wq.w;
            a[2][0] += z2 * wq.x; a[2][1] += z2 * wq.y;
            a[2][2] += z2 * wq.z; a[2][3] += z2 * wq.w;
            a[3][0] += z3 * wq.x; a[3][1] += z3 * wq.y;
            a[3][2] += z3 * wq.z; a[3][3] += z3 * wq.w;
        }
        #pragma unroll
        for (int ri = 0; ri < 4; ++ri) {
            half4v o;
            o.x = (half_t)fmaxf(a[ri][0], 0.0f); o.y = (half_t)fmaxf(a[ri][1], 0.0f);
            o.z = (half_t)fmaxf(a[ri][2], 0.0f); o.w = (half_t)fmaxf(a[ri][3], 0.0f);
            *reinterpret_cast<half4v*>(&ts[(rb + ri) * 132 + cb]) = o;
        }
    }
    __syncthreads();
    for (int idx = t; idx < 128 * 64; idx += 256) Ws[idx] = W4[idx];
    __syncthreads();

    // ---- layer 2: h2 = t @ W4 + b4 (row-major ts reads) ----
    {
        int cg2 = t & 15, rg = t >> 4;
        int cb = cg2 * 4, rb = rg * 2;
        float4 b4v = *reinterpret_cast<const float4*>(&b4[cb]);
        float a[2][4];
        #pragma unroll
        for (int ri = 0; ri < 2; ++ri) {
            a[ri][0] = b4v.x; a[ri][1] = b4v.y; a[ri][2] = b4v.z; a[ri][3] = b4v.w;
        }
        #pragma unroll 4
        for (int k = 0; k < 128; ++k) {
            float t0 = (float)ts[rb * 132 + k];
            float t1 = (float)ts[(rb + 1) * 132 + k];
            float4 wq = *reinterpret_cast<const float4*>(&Ws[k * 64 + cb]);
            a[0][0] += t0 * wq.x; a[0][1] += t0 * wq.y;
            a[0][2] += t0 * wq.z; a[0][3] += t0 * wq.w;
            a[1][0] += t1 * wq.x; a[1][1] += t1 * wq.y;
            a[1][2] += t1 * wq.z; a[1][3] += t1 * wq.w;
        }
        #pragma unroll
        for (int ri = 0; ri < 2; ++ri) {
            int r = rb + ri;
            if (r < rows) {
                float4 o = {a[ri][0], a[ri][1], a[ri][2], a[ri][3]};
                *reinterpret_cast<float4*>(&h2[(size_t)(r0 + r) * 64 + cb]) = o;
            }
        }
    }
}

// ---------------- propagation, channel-split planes ----------------
// z stored as TWO separate fp16 planes of 32 ch (3.2 MB each < 4 MB L2/XCD).
// blockIdx & 7 ~ XCD (round-robin heuristic): XCD 0-3 -> plane 0, 4-7 -> plane 1,
// so each XCD's random gathers stay within one L2-resident plane.
// Wave = 1 node: 8 edge slots (g) x 8 lanes x 4 ch (8 B/lane, 512 B/gather).
// Rows padded to x8 -> no tails. shfl_xor 8/16/32 reduces slots; (lane&7) kept.

__device__ inline void roundH(const half_t* __restrict__ zin,
                              const int* __restrict__ edata, int e, int g, int c4,
                              float4& a, float& vacc, const float* __restrict__ vin,
                              bool withv, int firstOnes) {
    unsigned int pk = (unsigned int)edata[e + g];
    int sn = pk >> 15;
    float n = h15_2f(pk);                      // pad slots: n == 0
    float4 z = h4tof4(&zin[(size_t)sn * 32 + c4]);
    if (withv) vacc += firstOnes ? n : n * vin[sn];
    a.x += n * z.x; a.y += n * z.y; a.z += n * z.z; a.w += n * z.w;
}

__device__ inline void roundF(const float* __restrict__ gsrc,
                              const int* __restrict__ edata, int e, int g, int choff,
                              float4& a, float& vacc, const float* __restrict__ vin,
                              bool withv, int firstOnes) {
    unsigned int pk = (unsigned int)edata[e + g];
    int sn = pk >> 15;
    float n = h15_2f(pk);
    float4 z = *reinterpret_cast<const float4*>(&gsrc[(size_t)sn * 64 + choff]);
    if (withv) vacc += firstOnes ? n : n * vin[sn];
    a.x += n * z.x; a.y += n * z.y; a.z += n * z.z; a.w += n * z.w;
}

template <bool WITHV>
__global__ __launch_bounds__(256) void prophalf_kernel(
        const half_t* __restrict__ zinP0, const half_t* __restrict__ zinP1,
        half_t* __restrict__ zoutP0, half_t* __restrict__ zoutP1,
        const float* __restrict__ gsrcF,   // fp32 gather source (step 0)
        const float* __restrict__ hsrc,    // alpha-term rows fp32 [N][64]
        const int* __restrict__ rowptr, const int* __restrict__ edata,
        const float* __restrict__ dinv,
        float* __restrict__ outF,          // final fp32 out (lastOut)
        const float* __restrict__ vin, float* __restrict__ vout,
        int N, int blocksPerXcd, int s0, int lastOut, int firstOnes) {
    const int wave = threadIdx.x >> 6;
    const int lane = threadIdx.x & 63;
    const int g = lane >> 3;               // edge slot 0..7
    const int c4 = (lane & 7) << 2;        // channel base within plane (4 ch/lane)
    const int r = blockIdx.x & 7;          // XCD (heuristic)
    const int p = r >> 2;                  // plane 0: XCD 0-3, plane 1: XCD 4-7
    const int seq = (r & 3) * blocksPerXcd + (blockIdx.x >> 3);  // contiguous/XCD
    const int node = seq * 4 + wave;
    if (node >= N) return;
    const int nd = __builtin_amdgcn_readfirstlane(node);

    const half_t* zin = p ? zinP1 : zinP0;
    const int choff = (p << 5) + c4;
    const bool withv = WITHV && (p == 0);  // v computed on plane 0 only

    int beg = rowptr[nd];
    int end = rowptr[nd + 1];              // multiple of 8 slots
    float4 a = {0.f, 0.f, 0.f, 0.f};
    float vacc = 0.f;

    if (s0) {
        int e = beg;
        for (; e + 16 <= end; e += 16) {
            roundF(gsrcF, edata, e, g, choff, a, vacc, vin, withv, firstOnes);
            roundF(gsrcF, edata, e + 8, g, choff, a, vacc, vin, withv, firstOnes);
        }
        if (e < end)
            roundF(gsrcF, edata, e, g, choff, a, vacc, vin, withv, firstOnes);
    } else {
        int e = beg;
        for (; e + 16 <= end; e += 16) {
            roundH(zin, edata, e, g, c4, a, vacc, vin, withv, firstOnes);
            roundH(zin, edata, e + 8, g, c4, a, vacc, vin, withv, firstOnes);
        }
        if (e < end)
            roundH(zin, edata, e, g, c4, a, vacc, vin, withv, firstOnes);
    }

    // reduce across the 8 edge slots; (lane&7) -> channel slice preserved
    #pragma unroll
    for (int m = 8; m <= 32; m <<= 1) {
        a.x += __shfl_xor(a.x, m); a.y += __shfl_xor(a.y, m);
        a.z += __shfl_xor(a.z, m); a.w += __shfl_xor(a.w, m);
        if (WITHV) vacc += __shfl_xor(vacc, m);
    }

    if (lane < 8) {                        // lane&7 == lane -> c4 = lane*4
        size_t pbase = (size_t)nd * 32 + (lane << 2);
        size_t fbase = (size_t)nd * 64 + (p << 5) + (lane << 2);
        float di = dinv[nd];
        float dd = di * di;
        float4 self = s0 ? *reinterpret_cast<const float4*>(&gsrcF[fbase])
                         : h4tof4(&zin[pbase]);
        float4 hh = *reinterpret_cast<const float4*>(&hsrc[fbase]);
        float4 rr;
        rr.x = (1.0f - PROP_ALPHA) * (a.x + dd * self.x) + PROP_ALPHA * hh.x;
        rr.y = (1.0f - PROP_ALPHA) * (a.y + dd * self.y) + PROP_ALPHA * hh.y;
        rr.z = (1.0f - PROP_ALPHA) * (a.z + dd * self.z) + PROP_ALPHA * hh.z;
        rr.w = (1.0f - PROP_ALPHA) * (a.w + dd * self.w) + PROP_ALPHA * hh.w;
        if (lastOut) {
            *reinterpret_cast<float4*>(&outF[fbase]) = rr;
        } else {
            half4v o;
            o.x = (half_t)rr.x; o.y = (half_t)rr.y;
            o.z = (half_t)rr.z; o.w = (half_t)rr.w;
            *reinterpret_cast<half4v*>(&(p ? zoutP1 : zoutP0)[pbase]) = o;
        }
        if (withv && lane == 0) {
            float selfv = firstOnes ? 1.0f : vin[nd];
            vout[nd] = (1.0f - PROP_ALPHA) * (vacc + dd * selfv) + PROP_ALPHA;
        }
    }
}

// ---------------- launch ----------------

extern "C" void kernel_launch(void* const* d_in, const int* in_sizes, int n_in,
                              void* d_out, int out_size, void* d_ws, size_t ws_size,
                              hipStream_t stream) {
    const float* x  = (const float*)d_in[0];
    const int*   ei = (const int*)d_in[1];
    const float* W3 = (const float*)d_in[2];
    const float* b3 = (const float*)d_in[3];
    const float* W4 = (const float*)d_in[4];
    const float* b4 = (const float*)d_in[5];
    float* out = (float*)d_out;

    int N = in_sizes[0] / 64;   // IN_CH = 64
    int E = in_sizes[1] / 2;
    const int* srcA = ei;
    const int* dstA = ei + E;

    char* ws = (char*)d_ws;
    size_t off = 0;
    auto alloc = [&](size_t bytes) -> void* {
        void* p = ws + off;
        off = (off + bytes + 255) & ~(size_t)255;
        return p;
    };

    int nScanB = (N + 255) / 256;
    size_t ePadMax = (size_t)E + 8 * (size_t)N;   // upper bound on padded slots

    int*    degI   = (int*)alloc((size_t)N * 4);
    int*    rowptr = (int*)alloc(((size_t)N + 1) * 4);
    int*    rowctr = (int*)alloc((size_t)N * 4);
    int*    bsums  = (int*)alloc((size_t)nScanB * 4);
    float*  dinv   = (float*)alloc((size_t)N * 4);
    int*    edata  = (int*)alloc(ePadMax * 4);
    float*  vA     = (float*)alloc((size_t)N * 4);
    float*  vB     = (float*)alloc((size_t)N * 4);
    half_t* zLoA   = (half_t*)alloc((size_t)N * 32 * 2);   // plane ch 0-31, buf A
    half_t* zHiA   = (half_t*)alloc((size_t)N * 32 * 2);   // plane ch 32-63, buf A
    half_t* zLoB   = (half_t*)alloc((size_t)N * 32 * 2);
    half_t* zHiB   = (half_t*)alloc((size_t)N * 32 * 2);
    float*  hbuf   = (float*)alloc((size_t)N * 64 * 4);

    hipMemsetAsync(degI, 0, (size_t)N * 4, stream);
    hipMemsetAsync(rowctr, 0, (size_t)N * 4, stream);
    hipMemsetAsync(edata, 0, ePadMax * 4, stream);   // pad slots read as norm=0

    // --- CSR build (padded rows) ---
    hist_kernel<<<(E + 255) / 256, 256, 0, stream>>>(dstA, degI, E);
    dinv_kernel<<<(N + 255) / 256, 256, 0, stream>>>(degI, dinv, N);
    scan1_kernel<<<nScanB, 256, 0, stream>>>(degI, rowptr, bsums, N);
    scan2_kernel<<<1, 256, 0, stream>>>(bsums, nScanB);
    scan3_kernel<<<nScanB, 256, 0, stream>>>(rowptr, bsums, N);
    scatter_kernel<<<(E + 255) / 256, 256, 0, stream>>>(srcA, dstA, rowptr, rowctr,
                                                        dinv, edata, E);

    int blocksPerPlane = (N + 3) / 4;                 // 4 waves/block, 1 node/wave
    int blocksPerXcd = (blocksPerPlane + 3) / 4;      // 4 XCDs per plane
    int grid = blocksPerXcd * 8;

    // --- prop1: zx = M^10*x (fp16 planes), fused v = M^10*ones ---
    // s=0: out planes A; odd s: A->B; even s: B->A; s=9 -> planes B
    for (int s = 0; s < PROP_KSTEPS; ++s) {
        const half_t* ziL = (s & 1) ? zLoA : zLoB;
        const half_t* ziH = (s & 1) ? zHiA : zHiB;
        half_t* zoL = (s & 1) ? zLoB : zLoA;
        half_t* zoH = (s & 1) ? zHiB : zHiA;
        const float* vi = (s & 1) ? vA : vB;          // s0: unused (firstOnes)
        float*       vo = (s & 1) ? vB : vA;
        prophalf_kernel<true><<<grid, 256, 0, stream>>>(
            ziL, ziH, zoL, zoH, x, x, rowptr, edata, dinv, nullptr,
            vi, vo, N, blocksPerXcd, (s == 0) ? 1 : 0, 0, (s == 0) ? 1 : 0);
    }
    // zx planes in zLoB/zHiB, v in vB

    // --- h2 = relu(zx@W3 + v*b3^T)@W4 + b4 ---
    fusedmlp_kernel<<<(N + 31) / 32, 256, 0, stream>>>(zLoB, zHiB, vB, W3, b3, W4, b4,
                                                       hbuf, N);

    // --- prop2: out = M^10*h2 ---
    for (int s = 0; s < PROP_KSTEPS; ++s) {
        const half_t* ziL = (s & 1) ? zLoA : zLoB;
        const half_t* ziH = (s & 1) ? zHiA : zHiB;
        half_t* zoL = (s & 1) ? zLoB : zLoA;
        half_t* zoH = (s & 1) ? zHiB : zHiA;
        int last = (s == PROP_KSTEPS - 1) ? 1 : 0;
        prophalf_kernel<false><<<grid, 256, 0, stream>>>(
            ziL, ziH, zoL, zoH, hbuf, hbuf, rowptr, edata, dinv, out,
            nullptr, nullptr, N, blocksPerXcd, (s == 0) ? 1 : 0, last, 0);
    }
}

// Round 5
// 626.163 us; speedup vs baseline: 7.4082x; 1.5929x over previous
//
#include <hip/hip_runtime.h>

#define PROP_ALPHA 0.1f
#define PROP_KSTEPS 10

typedef _Float16 half_t;
typedef __attribute__((ext_vector_type(4))) _Float16 half4v;
typedef __attribute__((ext_vector_type(8))) _Float16 half8v;

__device__ inline unsigned int f2h15(float w) {
    half_t h = (half_t)w;
    return (unsigned int)__builtin_bit_cast(unsigned short, h) & 0x7FFFu;
}
__device__ inline float h15_2f(unsigned int bits) {
    half_t h = __builtin_bit_cast(half_t, (unsigned short)(bits & 0x7FFFu));
    return (float)h;
}

// ---------------- CSR build ----------------

__global__ void hist_kernel(const int* __restrict__ dst, int* __restrict__ degI, int E) {
    int e = blockIdx.x * blockDim.x + threadIdx.x;
    if (e < E) atomicAdd(&degI[dst[e]], 1);
}

__global__ void dinv_kernel(const int* __restrict__ degI, float* __restrict__ dinv, int N) {
    int i = blockIdx.x * blockDim.x + threadIdx.x;
    if (i < N) {
        float d = (float)(degI[i] + 1);   // + self loop
        dinv[i] = rsqrtf(d);
    }
}

// rows padded to multiple of 8 slots (pad entries stay 0 => norm 0, src 0)
__global__ __launch_bounds__(256) void scan1_kernel(const int* __restrict__ degI,
                                                    int* __restrict__ rowptr,
                                                    int* __restrict__ blockSums, int N) {
    __shared__ int s[256];
    int t = threadIdx.x;
    int idx = blockIdx.x * 256 + t;
    s[t] = (idx < N) ? ((degI[idx] + 7) & ~7) : 0;
    __syncthreads();
    for (int off = 1; off < 256; off <<= 1) {
        int x = (t >= off) ? s[t - off] : 0;
        __syncthreads();
        s[t] += x;
        __syncthreads();
    }
    if (idx < N) rowptr[idx + 1] = s[t];
    if (t == 255) blockSums[blockIdx.x] = s[255];
    if (blockIdx.x == 0 && t == 0) rowptr[0] = 0;
}

__global__ __launch_bounds__(256) void scan2_kernel(int* __restrict__ blockSums, int nB) {
    __shared__ int s[256];
    int t = threadIdx.x;
    s[t] = (t < nB) ? blockSums[t] : 0;
    __syncthreads();
    for (int off = 1; off < 256; off <<= 1) {
        int x = (t >= off) ? s[t - off] : 0;
        __syncthreads();
        s[t] += x;
        __syncthreads();
    }
    if (t < nB) blockSums[t] = (t == 0) ? 0 : s[t - 1];
}

__global__ void scan3_kernel(int* __restrict__ rowptr, const int* __restrict__ blockSums,
                             int N) {
    int idx = blockIdx.x * 256 + threadIdx.x;
    if (idx < N) rowptr[idx + 1] += blockSums[blockIdx.x];
}

// edata[p] = src<<15 | fp16bits(norm) sans sign — plain store (L2-resident)
__global__ void scatter_kernel(const int* __restrict__ src, const int* __restrict__ dst,
                               const int* __restrict__ rowptr, int* __restrict__ rowctr,
                               const float* __restrict__ dinv,
                               int* __restrict__ edata, int E) {
    int e = blockIdx.x * blockDim.x + threadIdx.x;
    if (e < E) {
        int d = dst[e], s = src[e];
        int p = rowptr[d] + atomicAdd(&rowctr[d], 1);
        edata[p] = (int)(((unsigned int)s << 15) | f2h15(dinv[s] * dinv[d]));
    }
}

// ---------------- prep: z16 = (h)src, ah16 = (h)(alpha*src) ----------------

__global__ void prep_kernel(const float* __restrict__ src, half_t* __restrict__ z16,
                            half_t* __restrict__ ah16, int nvec) {
    int i = blockIdx.x * blockDim.x + threadIdx.x;
    if (i < nvec) {
        float4 v = reinterpret_cast<const float4*>(src)[i];
        half4v z;
        z.x = (half_t)v.x; z.y = (half_t)v.y; z.z = (half_t)v.z; z.w = (half_t)v.w;
        reinterpret_cast<half4v*>(z16)[i] = z;
        half4v a;
        a.x = (half_t)(PROP_ALPHA * v.x); a.y = (half_t)(PROP_ALPHA * v.y);
        a.z = (half_t)(PROP_ALPHA * v.z); a.w = (half_t)(PROP_ALPHA * v.w);
        reinterpret_cast<half4v*>(ah16)[i] = a;
    }
}

// ---------------- fused MLP: writes z16o = (h)h2, ah16o = (h)(alpha*h2) ------
// h2 = relu(zx@W3 + v*b3^T)@W4 + b4. hbuf eliminated.

__global__ __launch_bounds__(256) void fusedmlp_kernel(const half_t* __restrict__ zx,
                                                       const float* __restrict__ v,
                                                       const float* __restrict__ W3,
                                                       const float* __restrict__ b3,
                                                       const float* __restrict__ W4,
                                                       const float* __restrict__ b4,
                                                       half_t* __restrict__ z16o,
                                                       half_t* __restrict__ ah16o,
                                                       int N) {
    __shared__ float Ws[64 * 128];     // 32 KB: W3 [k][128] then W4 [k][64]
    __shared__ half_t zsT[64 * 36];    // [k][row] fp16, padded stride 36
    __shared__ half_t ts[32 * 132];    // [row][k] fp16, padded stride 132
    __shared__ float vs[32];
    int t = threadIdx.x;
    int r0 = blockIdx.x * 32;
    int rows = min(32, N - r0);

    for (int idx = t; idx < 64 * 128; idx += 256) Ws[idx] = W3[idx];
    for (int idx = t; idx < 32 * 64; idx += 256) {
        int r = idx >> 6, c = idx & 63;
        zsT[c * 36 + r] = (r < rows) ? zx[(size_t)(r0 + r) * 64 + c] : (half_t)0.0f;
    }
    if (t < 32) vs[t] = (t < rows) ? v[r0 + t] : 0.0f;
    __syncthreads();

    // ---- layer 1: ts = relu(z @ W3 + v*b3^T) ----
    {
        int cq = t & 31, rq = t >> 5;
        int cb = cq * 4, rb = rq * 4;
        float4 b3v = *reinterpret_cast<const float4*>(&b3[cb]);
        float a[4][4];
        #pragma unroll
        for (int ri = 0; ri < 4; ++ri) {
            float vv = vs[rb + ri];
            a[ri][0] = vv * b3v.x; a[ri][1] = vv * b3v.y;
            a[ri][2] = vv * b3v.z; a[ri][3] = vv * b3v.w;
        }
        #pragma unroll 4
        for (int k = 0; k < 64; ++k) {
            half4v zh = *reinterpret_cast<const half4v*>(&zsT[k * 36 + rb]);
            float z0 = (float)zh.x, z1 = (float)zh.y, z2 = (float)zh.z, z3 = (float)zh.w;
            float4 wq = *reinterpret_cast<const float4*>(&Ws[k * 128 + cb]);
            a[0][0] += z0 * wq.x; a[0][1] += z0 * wq.y;
            a[0][2] += z0 * wq.z; a[0][3] += z0 * wq.w;
            a[1][0] += z1 * wq.x; a[1][1] += z1 * wq.y;
            a[1][2] += z1 * wq.z; a[1][3] += z1 * wq.w;
            a[2][0] += z2 * wq.x; a[2][1] += z2 * wq.y;
            a[2][2] += z2 * wq.z; a[2][3] += z2 * wq.w;
            a[3][0] += z3 * wq.x; a[3][1] += z3 * wq.y;
            a[3][2] += z3 * wq.z; a[3][3] += z3 * wq.w;
        }
        #pragma unroll
        for (int ri = 0; ri < 4; ++ri) {
            half4v o;
            o.x = (half_t)fmaxf(a[ri][0], 0.0f); o.y = (half_t)fmaxf(a[ri][1], 0.0f);
            o.z = (half_t)fmaxf(a[ri][2], 0.0f); o.w = (half_t)fmaxf(a[ri][3], 0.0f);
            *reinterpret_cast<half4v*>(&ts[(rb + ri) * 132 + cb]) = o;
        }
    }
    __syncthreads();
    for (int idx = t; idx < 128 * 64; idx += 256) Ws[idx] = W4[idx];
    __syncthreads();

    // ---- layer 2: z16o/ah16o = t @ W4 + b4 (row-major ts reads) ----
    {
        int cg2 = t & 15, rg = t >> 4;
        int cb = cg2 * 4, rb = rg * 2;
        float4 b4v = *reinterpret_cast<const float4*>(&b4[cb]);
        float a[2][4];
        #pragma unroll
        for (int ri = 0; ri < 2; ++ri) {
            a[ri][0] = b4v.x; a[ri][1] = b4v.y; a[ri][2] = b4v.z; a[ri][3] = b4v.w;
        }
        #pragma unroll 4
        for (int k = 0; k < 128; ++k) {
            float t0 = (float)ts[rb * 132 + k];
            float t1 = (float)ts[(rb + 1) * 132 + k];
            float4 wq = *reinterpret_cast<const float4*>(&Ws[k * 64 + cb]);
            a[0][0] += t0 * wq.x; a[0][1] += t0 * wq.y;
            a[0][2] += t0 * wq.z; a[0][3] += t0 * wq.w;
            a[1][0] += t1 * wq.x; a[1][1] += t1 * wq.y;
            a[1][2] += t1 * wq.z; a[1][3] += t1 * wq.w;
        }
        #pragma unroll
        for (int ri = 0; ri < 2; ++ri) {
            int r = rb + ri;
            if (r < rows) {
                size_t base = (size_t)(r0 + r) * 64 + cb;
                half4v o;
                o.x = (half_t)a[ri][0]; o.y = (half_t)a[ri][1];
                o.z = (half_t)a[ri][2]; o.w = (half_t)a[ri][3];
                *reinterpret_cast<half4v*>(&z16o[base]) = o;
                half4v ao;
                ao.x = (half_t)(PROP_ALPHA * a[ri][0]);
                ao.y = (half_t)(PROP_ALPHA * a[ri][1]);
                ao.z = (half_t)(PROP_ALPHA * a[ri][2]);
                ao.w = (half_t)(PROP_ALPHA * a[ri][3]);
                *reinterpret_cast<half4v*>(&ah16o[base]) = ao;
            }
        }
    }
}

// ---------------- propagation ----------------
// Wave = 1 node. lane -> (edge slot g = lane>>3, channel base c = (lane&7)*8).
// Per 32-slot window: ONE coalesced edata load (lane<32) + __shfl distribution,
// then up to 4 row-gathers (8 x 128 B lines each) issued back-to-back ->
// ~32 lines in flight/wave. self + alpha*h (fp16) loads hoisted ahead of the
// gather phase. Rows padded to x8 -> no masks. shfl_xor 8/16/32 reduce.

template <bool WITHV>
__global__ __launch_bounds__(256, 8) void prop_kernel(
        const half_t* __restrict__ zin, const half_t* __restrict__ ah16,
        const int* __restrict__ rowptr, const int* __restrict__ edata,
        const float* __restrict__ dinv,
        half_t* __restrict__ zout, float* __restrict__ outF,
        const float* __restrict__ vin, float* __restrict__ vout,
        int N, int lastOut, int firstOnes) {
    const int wave = threadIdx.x >> 6;
    const int lane = threadIdx.x & 63;
    const int g = lane >> 3;              // edge slot 0..7
    const int c = (lane & 7) << 3;        // channel base (8 ch/lane, 16 B)
    int node = blockIdx.x * 4 + wave;
    if (node >= N) return;
    const int nd = __builtin_amdgcn_readfirstlane(node);
    int beg = rowptr[nd];
    int end = rowptr[nd + 1];             // end-beg multiple of 8

    // epilogue operands issued early (independent of gathers)
    half8v selfh = *reinterpret_cast<const half8v*>(&zin[(size_t)nd * 64 + c]);
    half8v ahh = *reinterpret_cast<const half8v*>(&ah16[(size_t)nd * 64 + c]);

    float a0=0.f,a1=0.f,a2=0.f,a3=0.f,a4=0.f,a5=0.f,a6=0.f,a7=0.f;
    float vacc = 0.f;
    int e = beg, slots = end - beg;

    while (slots > 0) {
        int w = slots < 32 ? slots : 32;
        int rr = w >> 3;                  // 1..4, wave-uniform
        unsigned ed = (lane < w) ? (unsigned)edata[e + lane] : 0u;
        unsigned pk0, pk1 = 0, pk2 = 0, pk3 = 0;
        half8v z0, z1, z2, z3;
        // issue all gathers before consuming any
        pk0 = (unsigned)__shfl((int)ed, g);
        z0 = *reinterpret_cast<const half8v*>(&zin[(size_t)(pk0 >> 15) * 64 + c]);
        if (rr > 1) {
            pk1 = (unsigned)__shfl((int)ed, 8 + g);
            z1 = *reinterpret_cast<const half8v*>(&zin[(size_t)(pk1 >> 15) * 64 + c]);
        }
        if (rr > 2) {
            pk2 = (unsigned)__shfl((int)ed, 16 + g);
            z2 = *reinterpret_cast<const half8v*>(&zin[(size_t)(pk2 >> 15) * 64 + c]);
        }
        if (rr > 3) {
            pk3 = (unsigned)__shfl((int)ed, 24 + g);
            z3 = *reinterpret_cast<const half8v*>(&zin[(size_t)(pk3 >> 15) * 64 + c]);
        }
        float v0 = 0.f, v1 = 0.f, v2 = 0.f, v3 = 0.f;
        if (WITHV && !firstOnes) {
            v0 = vin[pk0 >> 15];
            if (rr > 1) v1 = vin[pk1 >> 15];
            if (rr > 2) v2 = vin[pk2 >> 15];
            if (rr > 3) v3 = vin[pk3 >> 15];
        }
        {
            float n = h15_2f(pk0);                    // pads: n == 0
            if (WITHV) vacc += firstOnes ? n : n * v0;
            a0 += n*(float)z0[0]; a1 += n*(float)z0[1];
            a2 += n*(float)z0[2]; a3 += n*(float)z0[3];
            a4 += n*(float)z0[4]; a5 += n*(float)z0[5];
            a6 += n*(float)z0[6]; a7 += n*(float)z0[7];
        }
        if (rr > 1) {
            float n = h15_2f(pk1);
            if (WITHV) vacc += firstOnes ? n : n * v1;
            a0 += n*(float)z1[0]; a1 += n*(float)z1[1];
            a2 += n*(float)z1[2]; a3 += n*(float)z1[3];
            a4 += n*(float)z1[4]; a5 += n*(float)z1[5];
            a6 += n*(float)z1[6]; a7 += n*(float)z1[7];
        }
        if (rr > 2) {
            float n = h15_2f(pk2);
            if (WITHV) vacc += firstOnes ? n : n * v2;
            a0 += n*(float)z2[0]; a1 += n*(float)z2[1];
            a2 += n*(float)z2[2]; a3 += n*(float)z2[3];
            a4 += n*(float)z2[4]; a5 += n*(float)z2[5];
            a6 += n*(float)z2[6]; a7 += n*(float)z2[7];
        }
        if (rr > 3) {
            float n = h15_2f(pk3);
            if (WITHV) vacc += firstOnes ? n : n * v3;
            a0 += n*(float)z3[0]; a1 += n*(float)z3[1];
            a2 += n*(float)z3[2]; a3 += n*(float)z3[3];
            a4 += n*(float)z3[4]; a5 += n*(float)z3[5];
            a6 += n*(float)z3[6]; a7 += n*(float)z3[7];
        }
        e += w; slots -= w;
    }

    // reduce across the 8 edge slots; (lane&7) channel slice preserved
    #pragma unroll
    for (int m = 8; m <= 32; m <<= 1) {
        a0 += __shfl_xor(a0, m); a1 += __shfl_xor(a1, m);
        a2 += __shfl_xor(a2, m); a3 += __shfl_xor(a3, m);
        a4 += __shfl_xor(a4, m); a5 += __shfl_xor(a5, m);
        a6 += __shfl_xor(a6, m); a7 += __shfl_xor(a7, m);
        if (WITHV) vacc += __shfl_xor(vacc, m);
    }

    if (lane < 8) {                       // here c == lane*8
        float di = dinv[nd];
        float dd = di * di;
        const float om = 1.0f - PROP_ALPHA;
        float r0 = om * (a0 + dd * (float)selfh[0]) + (float)ahh[0];
        float r1 = om * (a1 + dd * (float)selfh[1]) + (float)ahh[1];
        float r2 = om * (a2 + dd * (float)selfh[2]) + (float)ahh[2];
        float r3 = om * (a3 + dd * (float)selfh[3]) + (float)ahh[3];
        float r4 = om * (a4 + dd * (float)selfh[4]) + (float)ahh[4];
        float r5 = om * (a5 + dd * (float)selfh[5]) + (float)ahh[5];
        float r6 = om * (a6 + dd * (float)selfh[6]) + (float)ahh[6];
        float r7 = om * (a7 + dd * (float)selfh[7]) + (float)ahh[7];
        size_t base = (size_t)nd * 64 + c;
        if (lastOut) {
            float4 o0 = {r0, r1, r2, r3};
            float4 o1 = {r4, r5, r6, r7};
            *reinterpret_cast<float4*>(&outF[base]) = o0;
            *reinterpret_cast<float4*>(&outF[base + 4]) = o1;
        } else {
            half8v o;
            o[0] = (half_t)r0; o[1] = (half_t)r1; o[2] = (half_t)r2; o[3] = (half_t)r3;
            o[4] = (half_t)r4; o[5] = (half_t)r5; o[6] = (half_t)r6; o[7] = (half_t)r7;
            *reinterpret_cast<half8v*>(&zout[base]) = o;
        }
        if (WITHV && lane == 0) {
            float selfv = firstOnes ? 1.0f : vin[nd];
            vout[nd] = (1.0f - PROP_ALPHA) * (vacc + dd * selfv) + PROP_ALPHA;
        }
    }
}

// ---------------- launch ----------------

extern "C" void kernel_launch(void* const* d_in, const int* in_sizes, int n_in,
                              void* d_out, int out_size, void* d_ws, size_t ws_size,
                              hipStream_t stream) {
    const float* x  = (const float*)d_in[0];
    const int*   ei = (const int*)d_in[1];
    const float* W3 = (const float*)d_in[2];
    const float* b3 = (const float*)d_in[3];
    const float* W4 = (const float*)d_in[4];
    const float* b4 = (const float*)d_in[5];
    float* out = (float*)d_out;

    int N = in_sizes[0] / 64;   // IN_CH = 64
    int E = in_sizes[1] / 2;
    const int* srcA = ei;
    const int* dstA = ei + E;

    char* ws = (char*)d_ws;
    size_t off = 0;
    auto alloc = [&](size_t bytes) -> void* {
        void* p = ws + off;
        off = (off + bytes + 255) & ~(size_t)255;
        return p;
    };

    int nScanB = (N + 255) / 256;
    size_t ePadMax = (size_t)E + 8 * (size_t)N;   // upper bound on padded slots

    int*    degI   = (int*)alloc((size_t)N * 4);
    int*    rowptr = (int*)alloc(((size_t)N + 1) * 4);
    int*    rowctr = (int*)alloc((size_t)N * 4);
    int*    bsums  = (int*)alloc((size_t)nScanB * 4);
    float*  dinv   = (float*)alloc((size_t)N * 4);
    int*    edata  = (int*)alloc(ePadMax * 4);
    float*  vA     = (float*)alloc((size_t)N * 4);
    float*  vB     = (float*)alloc((size_t)N * 4);
    half_t* z16A   = (half_t*)alloc((size_t)N * 64 * 2);
    half_t* z16B   = (half_t*)alloc((size_t)N * 64 * 2);
    half_t* ah16   = (half_t*)alloc((size_t)N * 64 * 2);

    hipMemsetAsync(degI, 0, (size_t)N * 4, stream);
    hipMemsetAsync(rowctr, 0, (size_t)N * 4, stream);
    hipMemsetAsync(edata, 0, ePadMax * 4, stream);   // pad slots read as norm=0

    // --- CSR build (padded rows) ---
    hist_kernel<<<(E + 255) / 256, 256, 0, stream>>>(dstA, degI, E);
    dinv_kernel<<<(N + 255) / 256, 256, 0, stream>>>(degI, dinv, N);
    scan1_kernel<<<nScanB, 256, 0, stream>>>(degI, rowptr, bsums, N);
    scan2_kernel<<<1, 256, 0, stream>>>(bsums, nScanB);
    scan3_kernel<<<nScanB, 256, 0, stream>>>(rowptr, bsums, N);
    scatter_kernel<<<(E + 255) / 256, 256, 0, stream>>>(srcA, dstA, rowptr, rowctr,
                                                        dinv, edata, E);

    int nvec = N * 16;                     // N*64/4 float4 groups
    int prepB = (nvec + 255) / 256;
    int propBlocks = (N + 3) / 4;          // 1 node/wave, 4 waves/block

    // --- phase 1: z16A = (h)x, ah16 = (h)(alpha*x); then 10 fp16 steps ---
    prep_kernel<<<prepB, 256, 0, stream>>>(x, z16A, ah16, nvec);
    for (int s = 0; s < PROP_KSTEPS; ++s) {
        const half_t* zi = (s & 1) ? z16B : z16A;
        half_t*       zo = (s & 1) ? z16A : z16B;
        const float*  vi = (s & 1) ? vB : vA;     // s0: unused (firstOnes)
        float*        vo = (s & 1) ? vA : vB;
        prop_kernel<true><<<propBlocks, 256, 0, stream>>>(
            zi, ah16, rowptr, edata, dinv, zo, nullptr, vi, vo, N, 0,
            (s == 0) ? 1 : 0);
    }
    // z in z16A (s9 writes z16A), v in vA

    // --- MLP: reads z16A, vA; writes z16B = (h)h2, ah16 = (h)(alpha*h2) ---
    fusedmlp_kernel<<<(N + 31) / 32, 256, 0, stream>>>(z16A, vA, W3, b3, W4, b4,
                                                       z16B, ah16, N);

    // --- phase 2: 10 fp16 steps from z16B; last step writes fp32 out ---
    for (int s = 0; s < PROP_KSTEPS; ++s) {
        const half_t* zi = (s & 1) ? z16A : z16B;
        half_t*       zo = (s & 1) ? z16B : z16A;
        int last = (s == PROP_KSTEPS - 1) ? 1 : 0;
        prop_kernel<false><<<propBlocks, 256, 0, stream>>>(
            zi, ah16, rowptr, edata, dinv, zo, out, nullptr, nullptr, N, last, 0);
    }
}

// Round 7
// 544.170 us; speedup vs baseline: 8.5245x; 1.1507x over previous
//
#include <hip/hip_runtime.h>

#define PROP_ALPHA 0.1f
#define PROP_KSTEPS 10

typedef _Float16 half_t;
typedef __attribute__((ext_vector_type(4))) _Float16 half4v;
typedef __attribute__((ext_vector_type(8))) _Float16 half8v;

// ---------------- CSR build ----------------

__global__ void hist_kernel(const int* __restrict__ dst, int* __restrict__ degI, int E) {
    int e = blockIdx.x * blockDim.x + threadIdx.x;
    if (e < E) atomicAdd(&degI[dst[e]], 1);
}

// dinv over N+1 (row N = zero sink for pad slots); also zero vA[N]/vB[N]
__global__ void dinvz_kernel(const int* __restrict__ degI, float* __restrict__ dinv,
                             float* __restrict__ vA, float* __restrict__ vB, int N) {
    int i = blockIdx.x * blockDim.x + threadIdx.x;
    if (i < N) {
        float d = (float)(degI[i] + 1);   // + self loop
        dinv[i] = rsqrtf(d);
    } else if (i == N) {
        dinv[N] = 0.0f;
        vA[N] = 0.0f;
        vB[N] = 0.0f;
    }
}

// rows padded to multiple of 4 slots (pad entries -> src N, w[N]=0)
__global__ __launch_bounds__(256) void scan1_kernel(const int* __restrict__ degI,
                                                    int* __restrict__ rowptr,
                                                    int* __restrict__ blockSums, int N) {
    __shared__ int s[256];
    int t = threadIdx.x;
    int idx = blockIdx.x * 256 + t;
    s[t] = (idx < N) ? ((degI[idx] + 3) & ~3) : 0;
    __syncthreads();
    for (int off = 1; off < 256; off <<= 1) {
        int x = (t >= off) ? s[t - off] : 0;
        __syncthreads();
        s[t] += x;
        __syncthreads();
    }
    if (idx < N) rowptr[idx + 1] = s[t];
    if (t == 255) blockSums[blockIdx.x] = s[255];
    if (blockIdx.x == 0 && t == 0) rowptr[0] = 0;
}

__global__ __launch_bounds__(256) void scan2_kernel(int* __restrict__ blockSums, int nB) {
    __shared__ int s[256];
    int t = threadIdx.x;
    s[t] = (t < nB) ? blockSums[t] : 0;
    __syncthreads();
    for (int off = 1; off < 256; off <<= 1) {
        int x = (t >= off) ? s[t - off] : 0;
        __syncthreads();
        s[t] += x;
        __syncthreads();
    }
    if (t < nB) blockSums[t] = (t == 0) ? 0 : s[t - 1];
}

__global__ void scan3_kernel(int* __restrict__ rowptr, const int* __restrict__ blockSums,
                             int N) {
    int idx = blockIdx.x * 256 + threadIdx.x;
    if (idx < N) rowptr[idx + 1] += blockSums[blockIdx.x];
}

// fill edata with the zero-sink index N (pads read w[N] = 0)
__global__ void fillu_kernel(unsigned int* __restrict__ p, unsigned int val, int n) {
    int i = blockIdx.x * blockDim.x + threadIdx.x;
    if (i < n) p[i] = val;
}

// edata[p] = src (u16) — norm is folded into w = dinv.z, nothing else needed
__global__ void scatter_kernel(const int* __restrict__ src, const int* __restrict__ dst,
                               const int* __restrict__ rowptr, int* __restrict__ rowctr,
                               unsigned short* __restrict__ edata, int E) {
    int e = blockIdx.x * blockDim.x + threadIdx.x;
    if (e < E) {
        int d = dst[e];
        int p = rowptr[d] + atomicAdd(&rowctr[d], 1);
        edata[p] = (unsigned short)src[e];
    }
}

// ---------------- prep: w0 = (h)(dinv*x), ah' = (h)(alpha*dinv*x); zero row N --

__global__ void prep_kernel(const float* __restrict__ x, const float* __restrict__ dinv,
                            half_t* __restrict__ z16A, half_t* __restrict__ z16B,
                            half_t* __restrict__ ah16, int N) {
    int i = blockIdx.x * blockDim.x + threadIdx.x;   // float4 groups
    int nvec = (N + 1) * 16;
    if (i >= nvec) return;
    int row = i >> 4;
    if (row < N) {
        float4 v = reinterpret_cast<const float4*>(x)[i];
        float di = dinv[row];
        half4v z;
        z.x = (half_t)(di * v.x); z.y = (half_t)(di * v.y);
        z.z = (half_t)(di * v.z); z.w = (half_t)(di * v.w);
        reinterpret_cast<half4v*>(z16A)[i] = z;
        half4v a;
        a.x = (half_t)(PROP_ALPHA * di * v.x); a.y = (half_t)(PROP_ALPHA * di * v.y);
        a.z = (half_t)(PROP_ALPHA * di * v.z); a.w = (half_t)(PROP_ALPHA * di * v.w);
        reinterpret_cast<half4v*>(ah16)[i] = a;
    } else {
        half4v zz = {(half_t)0.f, (half_t)0.f, (half_t)0.f, (half_t)0.f};
        reinterpret_cast<half4v*>(z16A)[i] = zz;   // zero sink row for pads
        reinterpret_cast<half4v*>(z16B)[i] = zz;
    }
}

// ---------------- fused MLP ----------------
// input w = dinv.z10 (fp16), vw = dinv.v ; z = w/dinv, v = vw/dinv staged.
// h2 = relu(z@W3 + v*b3^T)@W4 + b4 ; outputs w' = (h)(dinv*h2), ah' = (h)(a*dinv*h2).
// Weights read DIRECTLY from global (L1/L2-hot, same 64 KB for every block):
// LDS ~13 KB -> 8 blocks/CU (was 46 KB -> 3).

__global__ __launch_bounds__(256) void fusedmlp_kernel(const half_t* __restrict__ zx,
                                                       const float* __restrict__ vw,
                                                       const float* __restrict__ dinv,
                                                       const float* __restrict__ W3,
                                                       const float* __restrict__ b3,
                                                       const float* __restrict__ W4,
                                                       const float* __restrict__ b4,
                                                       half_t* __restrict__ z16o,
                                                       half_t* __restrict__ ah16o,
                                                       int N) {
    __shared__ half_t zsT[64 * 36];    // [k][row] fp16, padded stride 36
    __shared__ half_t ts[32 * 132];    // [row][k] fp16, padded stride 132
    __shared__ float vs[32];
    __shared__ float dis[32];
    __shared__ float rds[32];
    int t = threadIdx.x;
    int r0 = blockIdx.x * 32;
    int rows = min(32, N - r0);

    if (t < 32) {
        float di = (t < rows) ? dinv[r0 + t] : 1.0f;
        dis[t] = di;
        rds[t] = 1.0f / di;
        vs[t] = (t < rows) ? vw[r0 + t] / di : 0.0f;
    }
    __syncthreads();
    for (int idx = t; idx < 32 * 64; idx += 256) {
        int r = idx >> 6, c = idx & 63;
        float val = (r < rows) ? (float)zx[(size_t)(r0 + r) * 64 + c] * rds[r] : 0.0f;
        zsT[c * 36 + r] = (half_t)val;
    }
    __syncthreads();

    // ---- layer 1: ts = relu(z @ W3 + v*b3^T) ----
    {
        int cq = t & 31, rq = t >> 5;
        int cb = cq * 4, rb = rq * 4;
        float4 b3v = *reinterpret_cast<const float4*>(&b3[cb]);
        float a[4][4];
        #pragma unroll
        for (int ri = 0; ri < 4; ++ri) {
            float vv = vs[rb + ri];
            a[ri][0] = vv * b3v.x; a[ri][1] = vv * b3v.y;
            a[ri][2] = vv * b3v.z; a[ri][3] = vv * b3v.w;
        }
        #pragma unroll 4
        for (int k = 0; k < 64; ++k) {
            half4v zh = *reinterpret_cast<const half4v*>(&zsT[k * 36 + rb]);
            float z0 = (float)zh.x, z1 = (float)zh.y, z2 = (float)zh.z, z3 = (float)zh.w;
            float4 wq = *reinterpret_cast<const float4*>(&W3[k * 128 + cb]);
            a[0][0] += z0 * wq.x; a[0][1] += z0 * wq.y;
            a[0][2] += z0 * wq.z; a[0][3] += z0 * wq.w;
            a[1][0] += z1 * wq.x; a[1][1] += z1 * wq.y;
            a[1][2] += z1 * wq.z; a[1][3] += z1 * wq.w;
            a[2][0] += z2 * wq.x; a[2][1] += z2 * wq.y;
            a[2][2] += z2 * wq.z; a[2][3] += z2 * wq.w;
            a[3][0] += z3 * wq.x; a[3][1] += z3 * wq.y;
            a[3][2] += z3 * wq.z; a[3][3] += z3 * wq.w;
        }
        #pragma unroll
        for (int ri = 0; ri < 4; ++ri) {
            half4v o;
            o.x = (half_t)fmaxf(a[ri][0], 0.0f); o.y = (half_t)fmaxf(a[ri][1], 0.0f);
            o.z = (half_t)fmaxf(a[ri][2], 0.0f); o.w = (half_t)fmaxf(a[ri][3], 0.0f);
            *reinterpret_cast<half4v*>(&ts[(rb + ri) * 132 + cb]) = o;
        }
    }
    __syncthreads();

    // ---- layer 2: h2 = t @ W4 + b4; emit w' and ah' ----
    {
        int cg2 = t & 15, rg = t >> 4;
        int cb = cg2 * 4, rb = rg * 2;
        float4 b4v = *reinterpret_cast<const float4*>(&b4[cb]);
        float a[2][4];
        #pragma unroll
        for (int ri = 0; ri < 2; ++ri) {
            a[ri][0] = b4v.x; a[ri][1] = b4v.y; a[ri][2] = b4v.z; a[ri][3] = b4v.w;
        }
        #pragma unroll 4
        for (int k = 0; k < 128; ++k) {
            float t0 = (float)ts[rb * 132 + k];
            float t1 = (float)ts[(rb + 1) * 132 + k];
            float4 wq = *reinterpret_cast<const float4*>(&W4[k * 64 + cb]);
            a[0][0] += t0 * wq.x; a[0][1] += t0 * wq.y;
            a[0][2] += t0 * wq.z; a[0][3] += t0 * wq.w;
            a[1][0] += t1 * wq.x; a[1][1] += t1 * wq.y;
            a[1][2] += t1 * wq.z; a[1][3] += t1 * wq.w;
        }
        #pragma unroll
        for (int ri = 0; ri < 2; ++ri) {
            int r = rb + ri;
            if (r < rows) {
                float di = dis[r];
                size_t base = (size_t)(r0 + r) * 64 + cb;
                half4v o;
                o.x = (half_t)(di * a[ri][0]); o.y = (half_t)(di * a[ri][1]);
                o.z = (half_t)(di * a[ri][2]); o.w = (half_t)(di * a[ri][3]);
                *reinterpret_cast<half4v*>(&z16o[base]) = o;
                half4v ao;
                ao.x = (half_t)(PROP_ALPHA * di * a[ri][0]);
                ao.y = (half_t)(PROP_ALPHA * di * a[ri][1]);
                ao.z = (half_t)(PROP_ALPHA * di * a[ri][2]);
                ao.w = (half_t)(PROP_ALPHA * di * a[ri][3]);
                *reinterpret_cast<half4v*>(&ah16o[base]) = ao;
            }
        }
    }
}

// ---------------- propagation: w-state, group-per-node ----------------
// w = dinv.z: w_new[d] = (1-a)*dinv[d]^2*(sum_{s in N(d)} w[s] + w[d]) + ah'[d].
// 8-lane group = 1 node (8 ch x 8 lanes = full 64-ch row). 8 nodes/wave.
// Per 4 edges: ONE ushort4 edata load + 4 gathers (each 8x16 B = 1 line) ->
// 4 lines in flight per group, 32 per wave. No cross-lane reduction at all.
// Pads (to x4) point at zero row N. v piggybacks: vw_new = (1-a)*dd*(sum vw)+a*dinv,
// with vin = dinv at step 0 (since vw_0 = dinv).

template <bool WITHV>
__global__ __launch_bounds__(256, 8) void prop_kernel(
        const half_t* __restrict__ zin, const half_t* __restrict__ ah16,
        const int* __restrict__ rowptr, const unsigned short* __restrict__ edata,
        const float* __restrict__ dinv,
        half_t* __restrict__ zout, float* __restrict__ outF,
        const float* __restrict__ vin, float* __restrict__ vout,
        int N, int lastOut) {
    const int t = threadIdx.x;
    const int grp = t >> 3;               // node group 0..31 in block
    const int l8 = t & 7;                 // lane within group
    const int c = l8 << 3;                // channel base (8 ch, 16 B)
    int node = blockIdx.x * 32 + grp;
    if (node >= N) return;                // no barriers below: safe

    int beg = rowptr[node];
    int end = rowptr[node + 1];           // end-beg multiple of 4
    size_t selfbase = (size_t)node * 64 + c;

    half8v wself = *reinterpret_cast<const half8v*>(&zin[selfbase]);
    half8v ahh = *reinterpret_cast<const half8v*>(&ah16[selfbase]);
    float di = dinv[node];

    float acc[8];
    #pragma unroll
    for (int j = 0; j < 8; ++j) acc[j] = (float)wself[j];   // self term
    float vacc = WITHV ? vin[node] : 0.0f;                  // self vw

    for (int e = beg; e < end; e += 4) {
        ushort4 ss = *reinterpret_cast<const ushort4*>(&edata[e]);  // group-bcast
        half8v z0 = *reinterpret_cast<const half8v*>(&zin[(size_t)ss.x * 64 + c]);
        half8v z1 = *reinterpret_cast<const half8v*>(&zin[(size_t)ss.y * 64 + c]);
        half8v z2 = *reinterpret_cast<const half8v*>(&zin[(size_t)ss.z * 64 + c]);
        half8v z3 = *reinterpret_cast<const half8v*>(&zin[(size_t)ss.w * 64 + c]);
        if (WITHV)
            vacc += vin[ss.x] + vin[ss.y] + vin[ss.z] + vin[ss.w];  // bcast loads
        #pragma unroll
        for (int j = 0; j < 8; ++j) {
            acc[j] += (float)z0[j] + (float)z1[j];
            acc[j] += (float)z2[j] + (float)z3[j];
        }
    }

    const float om = 1.0f - PROP_ALPHA;
    float dd = di * di;
    if (!lastOut) {
        half8v o;
        #pragma unroll
        for (int j = 0; j < 8; ++j)
            o[j] = (half_t)(om * dd * acc[j] + (float)ahh[j]);
        *reinterpret_cast<half8v*>(&zout[selfbase]) = o;
    } else {
        float rd = 1.0f / di;             // z_out = (1-a)*dinv*S + ah'/dinv
        float r[8];
        #pragma unroll
        for (int j = 0; j < 8; ++j)
            r[j] = om * di * acc[j] + (float)ahh[j] * rd;
        float4 o0 = {r[0], r[1], r[2], r[3]};
        float4 o1 = {r[4], r[5], r[6], r[7]};
        *reinterpret_cast<float4*>(&outF[selfbase]) = o0;
        *reinterpret_cast<float4*>(&outF[selfbase + 4]) = o1;
    }
    if (WITHV && l8 == 0)
        vout[node] = om * dd * vacc + PROP_ALPHA * di;
}

// ---------------- launch ----------------

extern "C" void kernel_launch(void* const* d_in, const int* in_sizes, int n_in,
                              void* d_out, int out_size, void* d_ws, size_t ws_size,
                              hipStream_t stream) {
    const float* x  = (const float*)d_in[0];
    const int*   ei = (const int*)d_in[1];
    const float* W3 = (const float*)d_in[2];
    const float* b3 = (const float*)d_in[3];
    const float* W4 = (const float*)d_in[4];
    const float* b4 = (const float*)d_in[5];
    float* out = (float*)d_out;

    int N = in_sizes[0] / 64;   // IN_CH = 64 ; note: u16 edata requires N < 65536
    int E = in_sizes[1] / 2;
    const int* srcA = ei;
    const int* dstA = ei + E;

    char* ws = (char*)d_ws;
    size_t off = 0;
    auto alloc = [&](size_t bytes) -> void* {
        void* p = ws + off;
        off = (off + bytes + 255) & ~(size_t)255;
        return p;
    };

    int nScanB = (N + 255) / 256;
    size_t slotsMax = (size_t)E + 4 * (size_t)N;    // upper bound incl. padding

    int*    degI   = (int*)alloc((size_t)N * 4);
    int*    rowptr = (int*)alloc(((size_t)N + 1) * 4);
    int*    rowctr = (int*)alloc((size_t)N * 4);
    int*    bsums  = (int*)alloc((size_t)nScanB * 4);
    float*  dinv   = (float*)alloc(((size_t)N + 1) * 4);
    unsigned short* edata = (unsigned short*)alloc(slotsMax * 2 + 8);
    float*  vA     = (float*)alloc(((size_t)N + 1) * 4);
    float*  vB     = (float*)alloc(((size_t)N + 1) * 4);
    half_t* z16A   = (half_t*)alloc(((size_t)N + 1) * 64 * 2);
    half_t* z16B   = (half_t*)alloc(((size_t)N + 1) * 64 * 2);
    half_t* ah16   = (half_t*)alloc(((size_t)N + 1) * 64 * 2);

    hipMemsetAsync(degI, 0, (size_t)N * 4, stream);
    hipMemsetAsync(rowctr, 0, (size_t)N * 4, stream);

    // --- CSR build (rows padded to x4; pads = sink node N) ---
    int nFill = (int)((slotsMax + 1) / 2);
    unsigned int fillv = ((unsigned int)N << 16) | (unsigned int)N;
    fillu_kernel<<<(nFill + 255) / 256, 256, 0, stream>>>((unsigned int*)edata, fillv, nFill);
    hist_kernel<<<(E + 255) / 256, 256, 0, stream>>>(dstA, degI, E);
    dinvz_kernel<<<(N + 256) / 256, 256, 0, stream>>>(degI, dinv, vA, vB, N);
    scan1_kernel<<<nScanB, 256, 0, stream>>>(degI, rowptr, bsums, N);
    scan2_kernel<<<1, 256, 0, stream>>>(bsums, nScanB);
    scan3_kernel<<<nScanB, 256, 0, stream>>>(rowptr, bsums, N);
    scatter_kernel<<<(E + 255) / 256, 256, 0, stream>>>(srcA, dstA, rowptr, rowctr,
                                                        edata, E);

    int nvec = (N + 1) * 16;
    int propBlocks = (N + 31) / 32;        // 1 node / 8-lane group, 32 nodes/block

    // --- phase 1: w = dinv.x prepped; 10 steps; v tracked as vw ---
    prep_kernel<<<(nvec + 255) / 256, 256, 0, stream>>>(x, dinv, z16A, z16B, ah16, N);
    for (int s = 0; s < PROP_KSTEPS; ++s) {
        const half_t* zi = (s == 0) ? z16A : ((s & 1) ? z16B : z16A);
        half_t*       zo = (s == 0) ? z16B : ((s & 1) ? z16A : z16B);
        const float*  vi = (s == 0) ? dinv : ((s & 1) ? vA : vB);
        float*        vo = (s == 0) ? vA   : ((s & 1) ? vB : vA);
        prop_kernel<true><<<propBlocks, 256, 0, stream>>>(
            zi, ah16, rowptr, edata, dinv, zo, nullptr, vi, vo, N, 0);
    }
    // s0 A->B, s1 B->A, ..., s9 B->A: w10 in z16A, vw10 in vB.

    // --- MLP: z16A,vB -> z16B = w' = dinv*h2, ah16 = alpha*dinv*h2 ---
    fusedmlp_kernel<<<(N + 31) / 32, 256, 0, stream>>>(z16A, vB, dinv, W3, b3, W4, b4,
                                                       z16B, ah16, N);

    // --- phase 2: 10 steps from z16B; last step writes fp32 out ---
    for (int s = 0; s < PROP_KSTEPS; ++s) {
        const half_t* zi = (s & 1) ? z16A : z16B;
        half_t*       zo = (s & 1) ? z16B : z16A;
        int last = (s == PROP_KSTEPS - 1) ? 1 : 0;
        prop_kernel<false><<<propBlocks, 256, 0, stream>>>(
            zi, ah16, rowptr, edata, dinv, zo, out, nullptr, nullptr, N, last);
    }
}